// Round 10
// baseline (255.160 us; speedup 1.0000x reference)
//
#include <hip/hip_runtime.h>

#define S 2048
#define D 768
#define NH 12
#define HD 64
#define TD (3 * D)

typedef __bf16 bf16_t;
typedef __bf16 v8bf __attribute__((ext_vector_type(8)));
typedef __bf16 v4bf __attribute__((ext_vector_type(4)));
typedef float v4f __attribute__((ext_vector_type(4)));

// ---------- reductions ----------
__device__ __forceinline__ float wave_reduce_sum(float v) {
#pragma unroll
    for (int o = 32; o > 0; o >>= 1) v += __shfl_down(v, o, 64);
    return v;
}
__device__ float block_reduce_sum(float v) {
    __shared__ float t4[4];
    int lane = threadIdx.x & 63, wid = threadIdx.x >> 6;
    v = wave_reduce_sum(v);
    __syncthreads();
    if (lane == 0) t4[wid] = v;
    __syncthreads();
    return t4[0] + t4[1] + t4[2] + t4[3];
}

// ---------- fused: blocks [0,S) do add+LN; blocks [S,...) convert weights ----------
#define NW0 (TD * D / 4)
#define NW1 (D * D / 4)
#define NW2 ((D / 2) * D / 4)
#define NW3 (D * (D / 2) / 4)
#define NWALL (NW0 + NW1 + NW2 + NW3)

__global__ __launch_bounds__(256) void addln_cvt(const float* __restrict__ A, const float* __restrict__ Bv,
                                                 const float* __restrict__ g, const float* __restrict__ be,
                                                 bf16_t* __restrict__ out,
                                                 const float* __restrict__ s0, const float* __restrict__ s1,
                                                 const float* __restrict__ s2, const float* __restrict__ s3,
                                                 bf16_t* __restrict__ d0, bf16_t* __restrict__ d1,
                                                 bf16_t* __restrict__ d2, bf16_t* __restrict__ d3) {
    int blk = blockIdx.x, t = threadIdx.x;
    if (blk >= S) {
        int i = (blk - S) * 256 + t;
        const float* sp; bf16_t* dp;
        if (i < NW0) { sp = s0; dp = d0; }
        else if (i < NW0 + NW1) { sp = s1; dp = d1; i -= NW0; }
        else if (i < NW0 + NW1 + NW2) { sp = s2; dp = d2; i -= NW0 + NW1; }
        else if (i < NWALL) { sp = s3; dp = d3; i -= NW0 + NW1 + NW2; }
        else return;
        float4 v = ((const float4*)sp)[i];
        v4bf o = {(bf16_t)v.x, (bf16_t)v.y, (bf16_t)v.z, (bf16_t)v.w};
        *(v4bf*)(dp + (size_t)i * 4) = o;
        return;
    }
    int row = blk;
    const float* a = A + (size_t)row * D;
    const float* b = Bv + (size_t)row * D;
    float x[3];
    float s = 0.f;
#pragma unroll
    for (int i = 0; i < 3; ++i) { int c = t + 256 * i; x[i] = a[c] + b[c]; s += x[i]; }
    float mean = block_reduce_sum(s) * (1.0f / D);
    float vs = 0.f;
#pragma unroll
    for (int i = 0; i < 3; ++i) { float d = x[i] - mean; vs += d * d; }
    float var = block_reduce_sum(vs) * (1.0f / D);
    float rstd = rsqrtf(var + 1e-5f);
#pragma unroll
    for (int i = 0; i < 3; ++i) {
        int c = t + 256 * i;
        out[(size_t)row * D + c] = (bf16_t)((x[i] - mean) * rstd * g[c] + be[c]);
    }
}

// ---------- single-input LayerNorm ----------
template <typename TO>
__global__ __launch_bounds__(256) void ln_only(const bf16_t* __restrict__ X,
                                               const float* __restrict__ g, const float* __restrict__ be,
                                               TO* __restrict__ out) {
    int row = blockIdx.x, t = threadIdx.x;
    const bf16_t* a = X + (size_t)row * D;
    float x[3];
    float s = 0.f;
#pragma unroll
    for (int i = 0; i < 3; ++i) { int c = t + 256 * i; x[i] = (float)a[c]; s += x[i]; }
    float mean = block_reduce_sum(s) * (1.0f / D);
    float vs = 0.f;
#pragma unroll
    for (int i = 0; i < 3; ++i) { float d = x[i] - mean; vs += d * d; }
    float var = block_reduce_sum(vs) * (1.0f / D);
    float rstd = rsqrtf(var + 1e-5f);
#pragma unroll
    for (int i = 0; i < 3; ++i) {
        int c = t + 256 * i;
        out[(size_t)row * D + c] = (TO)((x[i] - mean) * rstd * g[c] + be[c]);
    }
}

// ---------- B-resident, barrier-free MFMA GEMM ----------
// C[2048, N] = act(A[2048,K] @ B[N,K]^T + bias) [+ Rsd].
// Block = 32-col B-strip (full K resident in LDS, staged once) x CH*32 rows.
// Waves 2x2: wm = row half (16-row chunks at wm*16 + 32*c), wn = col half.
// Main loop has NO barriers: per k-slab 1 ds_read_b128 (B-frag, reused CH times)
// + CH direct global->reg A-frag loads (16B/lane; pattern verified in r9) + CH
// MFMAs on independent accumulators.
// LDS layout [slab][kgroup g][row r]: elem off = slab*1024 + g*256 + r*8.
//  - staging chunk c = slab*128 + g*32 + r -> lds off 8c (lane-contiguous, as
//    global_load_lds requires); gsrc = B + (n0+r)*K + slab*32 + g*8.
//  - read addr (row=wn*16+lm, g=q): 16 lanes of a quarter-wave span 256B
//    contiguous -> 2 lanes/bank = conflict-free [m136].
template <int N, int K, int CH, int RELU, bool RESID>
__global__ __launch_bounds__(256) void gemm_bres(const bf16_t* __restrict__ A, const bf16_t* __restrict__ B,
                                                 const float* __restrict__ bias,
                                                 const bf16_t* __restrict__ Rsd, bf16_t* __restrict__ C) {
    constexpr int SLABS = K / 32;
    constexpr int PASSES = SLABS * 128 / 256;
    __shared__ bf16_t Bs[SLABS * 1024];
    const int t = threadIdx.x, lane = t & 63, wave = t >> 6;
    const int wm = wave >> 1, wn = wave & 1;
    const int lm = lane & 15, q = lane >> 4;
    const int n0 = blockIdx.x * 32;
    const int m0 = blockIdx.y * (CH * 32);

    // ---- stage B-strip once ----
#pragma unroll
    for (int p = 0; p < PASSES; ++p) {
        int c = t + 256 * p;
        int slab = c >> 7, g = (c >> 5) & 3, r = c & 31;
        __builtin_amdgcn_global_load_lds(
            (const __attribute__((address_space(1))) void*)(B + (size_t)(n0 + r) * K + slab * 32 + g * 8),
            (__attribute__((address_space(3))) void*)(Bs + c * 8), 16, 0, 0);
    }
    __syncthreads();  // only barrier in the kernel

    // ---- barrier-free main loop ----
    v4f acc[CH] = {};
    const bf16_t* Ab = A + (size_t)(m0 + wm * 16 + lm) * K + q * 8;
#pragma unroll 4
    for (int slab = 0; slab < SLABS; ++slab) {
        v8bf bfr = *(const v8bf*)(Bs + slab * 1024 + q * 256 + (wn * 16 + lm) * 8);
        v8bf af[CH];
#pragma unroll
        for (int c = 0; c < CH; ++c)
            af[c] = *(const v8bf*)(Ab + (size_t)(32 * c) * K + slab * 32);
#pragma unroll
        for (int c = 0; c < CH; ++c)
            acc[c] = __builtin_amdgcn_mfma_f32_16x16x32_bf16(af[c], bfr, acc[c], 0, 0, 0);
    }

    // ---- epilogue (D: row = q*4+reg, col = lane&15 — verified mapping) ----
    const int col = n0 + wn * 16 + lm;
    const float bb = bias[col];
#pragma unroll
    for (int c = 0; c < CH; ++c) {
#pragma unroll
        for (int r = 0; r < 4; ++r) {
            int row = m0 + wm * 16 + 32 * c + q * 4 + r;
            float v = acc[c][r] + bb;
            if (RELU) v = fmaxf(v, 0.f);
            if (RESID) v += (float)Rsd[(size_t)row * N + col];
            C[(size_t)row * N + col] = (bf16_t)v;
        }
    }
}

// ---------- sparse masked attention (block per row; conflict-free scores; ILP'd PV) ----------
__global__ __launch_bounds__(256) void attn_sparse(const bf16_t* __restrict__ qkv, const int* __restrict__ adj,
                                                   bf16_t* __restrict__ O) {
    __shared__ int s_idx[128];
    __shared__ int s_cnt;
    __shared__ float s_q[D];
    __shared__ float s_p[NH][128];

    const int row = blockIdx.x, t = threadIdx.x;
    const int lane = t & 63, wave = t >> 6;
    if (t == 0) s_cnt = 0;
    __syncthreads();

    const int4* arow = (const int4*)(adj + (size_t)row * S);
#pragma unroll
    for (int p = 0; p < 2; ++p) {
        int4 v = arow[t + 256 * p];
        int base = (t + 256 * p) * 4;
        if (v.x) { int k = atomicAdd(&s_cnt, 1); if (k < 128) s_idx[k] = base + 0; }
        if (v.y) { int k = atomicAdd(&s_cnt, 1); if (k < 128) s_idx[k] = base + 1; }
        if (v.z) { int k = atomicAdd(&s_cnt, 1); if (k < 128) s_idx[k] = base + 2; }
        if (v.w) { int k = atomicAdd(&s_cnt, 1); if (k < 128) s_idx[k] = base + 3; }
    }
    for (int c = t; c < D; c += 256) s_q[c] = (float)qkv[(size_t)row * TD + c];
    __syncthreads();
    const int n = (s_cnt < 128) ? s_cnt : 128;

    for (int it = t; it < n * NH; it += 256) {
        int h = it / n, i = it - h * n;
        int j = s_idx[i];
        const v8bf* kp = (const v8bf*)(qkv + (size_t)j * TD + D + h * HD);
        const float4* qp = (const float4*)(s_q + h * HD);
        float dot = 0.f;
#pragma unroll
        for (int c = 0; c < 8; ++c) {
            v8bf kv = kp[c];
            float4 qa = qp[2 * c], qb = qp[2 * c + 1];
            dot += qa.x * (float)kv[0] + qa.y * (float)kv[1] + qa.z * (float)kv[2] + qa.w * (float)kv[3]
                 + qb.x * (float)kv[4] + qb.y * (float)kv[5] + qb.z * (float)kv[6] + qb.w * (float)kv[7];
        }
        s_p[h][i] = dot * 0.125f;
    }
    __syncthreads();

    for (int h = wave; h < NH; h += 4) {
        float v0 = (lane < n) ? s_p[h][lane] : -1e30f;
        float v1 = (lane + 64 < n) ? s_p[h][lane + 64] : -1e30f;
        float m = fmaxf(v0, v1);
#pragma unroll
        for (int o = 32; o > 0; o >>= 1) m = fmaxf(m, __shfl_xor(m, o, 64));
        float p0 = (lane < n) ? __expf(v0 - m) : 0.f;
        float p1 = (lane + 64 < n) ? __expf(v1 - m) : 0.f;
        float sm = p0 + p1;
#pragma unroll
        for (int o = 32; o > 0; o >>= 1) sm += __shfl_xor(sm, o, 64);
        float inv = 1.f / sm;
        if (lane < n) s_p[h][lane] = p0 * inv;
        if (lane + 64 < n) s_p[h][lane + 64] = p1 * inv;
    }
    __syncthreads();

    for (int o = t; o < D; o += 256) {
        int h = o >> 6, e = o & 63;
        const float* pp = s_p[h];
        const bf16_t* vbase = qkv + 2 * D + h * HD + e;
        float a0 = 0.f, a1 = 0.f, a2 = 0.f, a3 = 0.f;
        int i = 0;
        for (; i + 4 <= n; i += 4) {
            int j0 = s_idx[i], j1 = s_idx[i + 1], j2 = s_idx[i + 2], j3 = s_idx[i + 3];
            a0 += pp[i]     * (float)vbase[(size_t)j0 * TD];
            a1 += pp[i + 1] * (float)vbase[(size_t)j1 * TD];
            a2 += pp[i + 2] * (float)vbase[(size_t)j2 * TD];
            a3 += pp[i + 3] * (float)vbase[(size_t)j3 * TD];
        }
        for (; i < n; ++i) a0 += pp[i] * (float)vbase[(size_t)s_idx[i] * TD];
        O[(size_t)row * D + o] = (bf16_t)((a0 + a1) + (a2 + a3));
    }
}

// ---------- launch ----------
extern "C" void kernel_launch(void* const* d_in, const int* in_sizes, int n_in,
                              void* d_out, int out_size, void* d_ws, size_t ws_size,
                              hipStream_t stream) {
    const float* exp_e = (const float*)d_in[0];
    const float* pert  = (const float*)d_in[1];
    const float* w_in  = (const float*)d_in[2];
    const float* b_in  = (const float*)d_in[3];
    const float* w_out = (const float*)d_in[4];
    const float* b_out = (const float*)d_in[5];
    const float* g0  = (const float*)d_in[6];
    const float* be0 = (const float*)d_in[7];
    const float* g1  = (const float*)d_in[8];
    const float* be1 = (const float*)d_in[9];
    const float* g2  = (const float*)d_in[10];
    const float* be2 = (const float*)d_in[11];
    const float* w1  = (const float*)d_in[12];
    const float* b1  = (const float*)d_in[13];
    const float* w2  = (const float*)d_in[14];
    const float* b2  = (const float*)d_in[15];
    const int*   adj = (const int*)d_in[16];
    float* out = (float*)d_out;

    const size_t SD = (size_t)S * D;
    bf16_t* wb_in  = (bf16_t*)d_ws;               // [2304*768]
    bf16_t* wb_out = wb_in + (size_t)TD * D;      // [768*768]
    bf16_t* wb_1   = wb_out + (size_t)D * D;      // [384*768]
    bf16_t* wb_2   = wb_1 + (size_t)(D / 2) * D;  // [768*384]
    bf16_t* x_in   = wb_2 + (size_t)D * (D / 2);  // [S*D]
    bf16_t* qkv    = x_in + SD;                   // [S*3D]
    bf16_t* attn_o = qkv + 3 * SD;                // [S*D]
    bf16_t* y1     = attn_o + SD;                 // [S*D] pre-LN1
    bf16_t* x1     = y1 + SD;                     // [S*D] ln1 out
    bf16_t* ffh    = x1 + SD;                     // [S*D/2]
    bf16_t* y2     = ffh + SD / 2;                // [S*D] pre-LN2

    const int CVTB = (NWALL + 255) / 256;
    addln_cvt<<<S + CVTB, 256, 0, stream>>>(exp_e, pert, g0, be0, x_in,
                                            w_in, w_out, w1, w2, wb_in, wb_out, wb_1, wb_2);
    // QKV: N=2304, K=768, CH=4 -> 128 rows/block, grid 72 x 16 = 1152
    gemm_bres<TD, D, 4, 0, false><<<dim3(TD / 32, S / 128), 256, 0, stream>>>(x_in, wb_in, b_in, nullptr, qkv);
    attn_sparse<<<S, 256, 0, stream>>>(qkv, adj, attn_o);
    // out-proj: N=768, K=768, CH=2 -> 64 rows/block, grid 24 x 32 = 768
    gemm_bres<D, D, 2, 0, true><<<dim3(D / 32, S / 64), 256, 0, stream>>>(attn_o, wb_out, b_out, x_in, y1);
    ln_only<bf16_t><<<S, 256, 0, stream>>>(y1, g1, be1, x1);
    // ff1: N=384, K=768, CH=2 -> grid 12 x 32 = 384
    gemm_bres<D / 2, D, 2, 1, false><<<dim3((D / 2) / 32, S / 64), 256, 0, stream>>>(x1, wb_1, b1, nullptr, ffh);
    // ff2: N=768, K=384, CH=2 -> grid 24 x 32 = 768
    gemm_bres<D, D / 2, 2, 0, true><<<dim3(D / 32, S / 64), 256, 0, stream>>>(ffh, wb_2, b2, x1, y2);
    ln_only<float><<<S, 256, 0, stream>>>(y2, g2, be2, out);
}

// Round 11
// 201.768 us; speedup vs baseline: 1.2646x; 1.2646x over previous
//
#include <hip/hip_runtime.h>

#define S 2048
#define D 768
#define NH 12
#define HD 64
#define TD (3 * D)

typedef __bf16 bf16_t;
typedef __bf16 v8bf __attribute__((ext_vector_type(8)));
typedef __bf16 v4bf __attribute__((ext_vector_type(4)));
typedef float v4f __attribute__((ext_vector_type(4)));

// ---------- reductions ----------
__device__ __forceinline__ float wave_reduce_sum(float v) {
#pragma unroll
    for (int o = 32; o > 0; o >>= 1) v += __shfl_down(v, o, 64);
    return v;
}
__device__ float block_reduce_sum(float v) {
    __shared__ float t4[4];
    int lane = threadIdx.x & 63, wid = threadIdx.x >> 6;
    v = wave_reduce_sum(v);
    __syncthreads();
    if (lane == 0) t4[wid] = v;
    __syncthreads();
    return t4[0] + t4[1] + t4[2] + t4[3];
}

// ---------- fused: blocks [0,S) add+LN; [S,S+CVTB) weight cvt; [S+CVTB,+S) adj->CSR ----------
#define NW0 (TD * D / 4)
#define NW1 (D * D / 4)
#define NW2 ((D / 2) * D / 4)
#define NW3 (D * (D / 2) / 4)
#define NWALL (NW0 + NW1 + NW2 + NW3)
#define CVTB ((NWALL + 255) / 256)

__global__ __launch_bounds__(256) void addln_cvt(const float* __restrict__ A, const float* __restrict__ Bv,
                                                 const float* __restrict__ g, const float* __restrict__ be,
                                                 bf16_t* __restrict__ out,
                                                 const float* __restrict__ s0, const float* __restrict__ s1,
                                                 const float* __restrict__ s2, const float* __restrict__ s3,
                                                 bf16_t* __restrict__ d0, bf16_t* __restrict__ d1,
                                                 bf16_t* __restrict__ d2, bf16_t* __restrict__ d3,
                                                 const int* __restrict__ adj,
                                                 int* __restrict__ csr_cnt, int* __restrict__ csr_idx) {
    int blk = blockIdx.x, t = threadIdx.x;
    if (blk >= S + CVTB) {
        // ---- adjacency row -> CSR (cnt + up to 128 indices) ----
        __shared__ int sc_idx[128];
        __shared__ int sc_cnt;
        int row = blk - S - CVTB;
        if (t == 0) sc_cnt = 0;
        __syncthreads();
        const int4* arow = (const int4*)(adj + (size_t)row * S);
#pragma unroll
        for (int p = 0; p < 2; ++p) {
            int4 v = arow[t + 256 * p];
            int base = (t + 256 * p) * 4;
            if (v.x) { int k = atomicAdd(&sc_cnt, 1); if (k < 128) sc_idx[k] = base + 0; }
            if (v.y) { int k = atomicAdd(&sc_cnt, 1); if (k < 128) sc_idx[k] = base + 1; }
            if (v.z) { int k = atomicAdd(&sc_cnt, 1); if (k < 128) sc_idx[k] = base + 2; }
            if (v.w) { int k = atomicAdd(&sc_cnt, 1); if (k < 128) sc_idx[k] = base + 3; }
        }
        __syncthreads();
        int n = (sc_cnt < 128) ? sc_cnt : 128;
        if (t == 0) csr_cnt[row] = n;
        if (t < n) csr_idx[(size_t)row * 128 + t] = sc_idx[t];
        return;
    }
    if (blk >= S) {
        int i = (blk - S) * 256 + t;
        const float* sp; bf16_t* dp;
        if (i < NW0) { sp = s0; dp = d0; }
        else if (i < NW0 + NW1) { sp = s1; dp = d1; i -= NW0; }
        else if (i < NW0 + NW1 + NW2) { sp = s2; dp = d2; i -= NW0 + NW1; }
        else if (i < NWALL) { sp = s3; dp = d3; i -= NW0 + NW1 + NW2; }
        else return;
        float4 v = ((const float4*)sp)[i];
        v4bf o = {(bf16_t)v.x, (bf16_t)v.y, (bf16_t)v.z, (bf16_t)v.w};
        *(v4bf*)(dp + (size_t)i * 4) = o;
        return;
    }
    int row = blk;
    const float* a = A + (size_t)row * D;
    const float* b = Bv + (size_t)row * D;
    float x[3];
    float s = 0.f;
#pragma unroll
    for (int i = 0; i < 3; ++i) { int c = t + 256 * i; x[i] = a[c] + b[c]; s += x[i]; }
    float mean = block_reduce_sum(s) * (1.0f / D);
    float vs = 0.f;
#pragma unroll
    for (int i = 0; i < 3; ++i) { float d = x[i] - mean; vs += d * d; }
    float var = block_reduce_sum(vs) * (1.0f / D);
    float rstd = rsqrtf(var + 1e-5f);
#pragma unroll
    for (int i = 0; i < 3; ++i) {
        int c = t + 256 * i;
        out[(size_t)row * D + c] = (bf16_t)((x[i] - mean) * rstd * g[c] + be[c]);
    }
}

// ---------- single-input LayerNorm ----------
template <typename TO>
__global__ __launch_bounds__(256) void ln_only(const bf16_t* __restrict__ X,
                                               const float* __restrict__ g, const float* __restrict__ be,
                                               TO* __restrict__ out) {
    int row = blockIdx.x, t = threadIdx.x;
    const bf16_t* a = X + (size_t)row * D;
    float x[3];
    float s = 0.f;
#pragma unroll
    for (int i = 0; i < 3; ++i) { int c = t + 256 * i; x[i] = (float)a[c]; s += x[i]; }
    float mean = block_reduce_sum(s) * (1.0f / D);
    float vs = 0.f;
#pragma unroll
    for (int i = 0; i < 3; ++i) { float d = x[i] - mean; vs += d * d; }
    float var = block_reduce_sum(vs) * (1.0f / D);
    float rstd = rsqrtf(var + 1e-5f);
#pragma unroll
    for (int i = 0; i < 3; ++i) {
        int c = t + 256 * i;
        out[(size_t)row * D + c] = (TO)((x[i] - mean) * rstd * g[c] + be[c]);
    }
}

// ---------- MFMA GEMM (r6-proven): BK=64 two-slab LDS, global_load_lds staging ----------
#define GBK 64

template <int TM, int TN, int RELU, bool RESID>
__global__ __launch_bounds__(256) void gemm_mfma(const bf16_t* __restrict__ A, const bf16_t* __restrict__ B,
                                                 const float* __restrict__ bias,
                                                 const bf16_t* __restrict__ Rsd, bf16_t* __restrict__ C,
                                                 int M, int N, int K) {
    constexpr int CA = TM * 8;
    constexpr int CHUNKS = (TM + TN) * 8;
    constexpr int P = CHUNKS / 256;
    static_assert(CHUNKS % 256 == 0, "chunk passes must be exact");
    constexpr int MI = TM / 32, NI = TN / 32;
    __shared__ bf16_t As[TM * GBK];
    __shared__ bf16_t Bs[TN * GBK];
    const int t = threadIdx.x;
    const int lane = t & 63, wave = t >> 6;
    const int wr = (wave >> 1) * (TM / 2), wc = (wave & 1) * (TN / 2);
    const int m0 = blockIdx.y * TM, n0 = blockIdx.x * TN;
    const int lm = lane & 15, q = lane >> 4;

    const bf16_t* gsrc[P];
    bf16_t* ldst[P];
#pragma unroll
    for (int p = 0; p < P; ++p) {
        int c = t + 256 * p;
        if (c < CA) {
            int slab = c / (TM * 4), r4 = c % (TM * 4);
            int row = r4 >> 2, c4 = r4 & 3;
            gsrc[p] = A + (size_t)(m0 + row) * K + slab * 32 + c4 * 8;
            ldst[p] = As + slab * (TM * 32) + row * 32 + c4 * 8;
        } else {
            int cc = c - CA;
            int slab = cc / (TN * 4), r4 = cc % (TN * 4);
            int row = r4 >> 2, c4 = r4 & 3;
            gsrc[p] = B + (size_t)(n0 + row) * K + slab * 32 + c4 * 8;
            ldst[p] = Bs + slab * (TN * 32) + row * 32 + c4 * 8;
        }
    }

    v4f acc[MI][NI] = {};

    for (int k0 = 0; k0 < K; k0 += GBK) {
#pragma unroll
        for (int p = 0; p < P; ++p)
            __builtin_amdgcn_global_load_lds((const __attribute__((address_space(1))) void*)(gsrc[p] + k0),
                                             (__attribute__((address_space(3))) void*)ldst[p], 16, 0, 0);
        __syncthreads();

        v8bf af[2][MI], bfr[2][NI];
#pragma unroll
        for (int s = 0; s < 2; ++s) {
#pragma unroll
            for (int i = 0; i < MI; ++i)
                af[s][i] = *(const v8bf*)(As + s * (TM * 32) + (wr + i * 16 + lm) * 32 + q * 8);
#pragma unroll
            for (int j = 0; j < NI; ++j)
                bfr[s][j] = *(const v8bf*)(Bs + s * (TN * 32) + (wc + j * 16 + lm) * 32 + q * 8);
        }
#pragma unroll
        for (int s = 0; s < 2; ++s)
#pragma unroll
            for (int i = 0; i < MI; ++i)
#pragma unroll
                for (int j = 0; j < NI; ++j)
                    acc[i][j] = __builtin_amdgcn_mfma_f32_16x16x32_bf16(af[s][i], bfr[s][j], acc[i][j], 0, 0, 0);
        __syncthreads();
    }

#pragma unroll
    for (int i = 0; i < MI; ++i)
#pragma unroll
        for (int j = 0; j < NI; ++j) {
            int col = n0 + wc + j * 16 + lm;
            float bs = bias[col];
#pragma unroll
            for (int r = 0; r < 4; ++r) {
                int row = m0 + wr + i * 16 + q * 4 + r;
                float v = acc[i][j][r] + bs;
                if (RELU) v = fmaxf(v, 0.f);
                if (RESID) v += (float)Rsd[(size_t)row * N + col];
                C[(size_t)row * N + col] = (bf16_t)v;
            }
        }
}

// ---------- sparse masked attention (CSR-fed; conflict-free scores; ILP'd PV) ----------
__global__ __launch_bounds__(256) void attn_sparse(const bf16_t* __restrict__ qkv,
                                                   const int* __restrict__ csr_cnt,
                                                   const int* __restrict__ csr_idx,
                                                   bf16_t* __restrict__ O) {
    __shared__ int s_idx[128];
    __shared__ float s_q[D];
    __shared__ float s_p[NH][128];

    const int row = blockIdx.x, t = threadIdx.x;
    const int lane = t & 63, wave = t >> 6;
    const int n = csr_cnt[row];            // 1..128 (diag forced)

    if (t < n) s_idx[t] = csr_idx[(size_t)row * 128 + t];
    for (int c = t; c < D; c += 256) s_q[c] = (float)qkv[(size_t)row * TD + c];
    __syncthreads();

    // scores: h = it/n, i = it%n (consecutive threads -> consecutive s_p[h][i])
    for (int it = t; it < n * NH; it += 256) {
        int h = it / n, i = it - h * n;
        int j = s_idx[i];
        const v8bf* kp = (const v8bf*)(qkv + (size_t)j * TD + D + h * HD);
        const float4* qp = (const float4*)(s_q + h * HD);
        float dot = 0.f;
#pragma unroll
        for (int c = 0; c < 8; ++c) {
            v8bf kv = kp[c];
            float4 qa = qp[2 * c], qb = qp[2 * c + 1];
            dot += qa.x * (float)kv[0] + qa.y * (float)kv[1] + qa.z * (float)kv[2] + qa.w * (float)kv[3]
                 + qb.x * (float)kv[4] + qb.y * (float)kv[5] + qb.z * (float)kv[6] + qb.w * (float)kv[7];
        }
        s_p[h][i] = dot * 0.125f;  // 1/sqrt(64)
    }
    __syncthreads();

    // softmax: 3 heads per wave, shuffle butterflies
    for (int h = wave; h < NH; h += 4) {
        float v0 = (lane < n) ? s_p[h][lane] : -1e30f;
        float v1 = (lane + 64 < n) ? s_p[h][lane + 64] : -1e30f;
        float m = fmaxf(v0, v1);
#pragma unroll
        for (int o = 32; o > 0; o >>= 1) m = fmaxf(m, __shfl_xor(m, o, 64));
        float p0 = (lane < n) ? __expf(v0 - m) : 0.f;
        float p1 = (lane + 64 < n) ? __expf(v1 - m) : 0.f;
        float sm = p0 + p1;
#pragma unroll
        for (int o = 32; o > 0; o >>= 1) sm += __shfl_xor(sm, o, 64);
        float inv = 1.f / sm;
        if (lane < n) s_p[h][lane] = p0 * inv;
        if (lane + 64 < n) s_p[h][lane + 64] = p1 * inv;
    }
    __syncthreads();

    // PV: 3 outputs/thread, 4 independent accumulation chains over keys
    for (int o = t; o < D; o += 256) {
        int h = o >> 6, e = o & 63;
        const float* pp = s_p[h];
        const bf16_t* vbase = qkv + 2 * D + h * HD + e;
        float a0 = 0.f, a1 = 0.f, a2 = 0.f, a3 = 0.f;
        int i = 0;
        for (; i + 4 <= n; i += 4) {
            int j0 = s_idx[i], j1 = s_idx[i + 1], j2 = s_idx[i + 2], j3 = s_idx[i + 3];
            a0 += pp[i]     * (float)vbase[(size_t)j0 * TD];
            a1 += pp[i + 1] * (float)vbase[(size_t)j1 * TD];
            a2 += pp[i + 2] * (float)vbase[(size_t)j2 * TD];
            a3 += pp[i + 3] * (float)vbase[(size_t)j3 * TD];
        }
        for (; i < n; ++i) a0 += pp[i] * (float)vbase[(size_t)s_idx[i] * TD];
        O[(size_t)row * D + o] = (bf16_t)((a0 + a1) + (a2 + a3));
    }
}

// ---------- launch ----------
extern "C" void kernel_launch(void* const* d_in, const int* in_sizes, int n_in,
                              void* d_out, int out_size, void* d_ws, size_t ws_size,
                              hipStream_t stream) {
    const float* exp_e = (const float*)d_in[0];
    const float* pert  = (const float*)d_in[1];
    const float* w_in  = (const float*)d_in[2];
    const float* b_in  = (const float*)d_in[3];
    const float* w_out = (const float*)d_in[4];
    const float* b_out = (const float*)d_in[5];
    const float* g0  = (const float*)d_in[6];
    const float* be0 = (const float*)d_in[7];
    const float* g1  = (const float*)d_in[8];
    const float* be1 = (const float*)d_in[9];
    const float* g2  = (const float*)d_in[10];
    const float* be2 = (const float*)d_in[11];
    const float* w1  = (const float*)d_in[12];
    const float* b1  = (const float*)d_in[13];
    const float* w2  = (const float*)d_in[14];
    const float* b2  = (const float*)d_in[15];
    const int*   adj = (const int*)d_in[16];
    float* out = (float*)d_out;

    const size_t SD = (size_t)S * D;
    bf16_t* wb_in  = (bf16_t*)d_ws;               // [2304*768]
    bf16_t* wb_out = wb_in + (size_t)TD * D;      // [768*768]
    bf16_t* wb_1   = wb_out + (size_t)D * D;      // [384*768]
    bf16_t* wb_2   = wb_1 + (size_t)(D / 2) * D;  // [768*384]
    bf16_t* x_in   = wb_2 + (size_t)D * (D / 2);  // [S*D]
    bf16_t* qkv    = x_in + SD;                   // [S*3D]
    bf16_t* attn_o = qkv + 3 * SD;                // [S*D]
    bf16_t* y1     = attn_o + SD;                 // [S*D] pre-LN1
    bf16_t* x1     = y1 + SD;                     // [S*D] ln1 out
    bf16_t* ffh    = x1 + SD;                     // [S*D/2]
    bf16_t* y2     = ffh + SD / 2;                // [S*D] pre-LN2
    int* csr_cnt   = (int*)(y2 + SD);             // [S]
    int* csr_idx   = csr_cnt + S;                 // [S*128]

    addln_cvt<<<S + CVTB + S, 256, 0, stream>>>(exp_e, pert, g0, be0, x_in,
                                                w_in, w_out, w1, w2, wb_in, wb_out, wb_1, wb_2,
                                                adj, csr_cnt, csr_idx);
    gemm_mfma<64, 128, 0, false><<<dim3(TD / 128, S / 64), 256, 0, stream>>>(x_in, wb_in, b_in, nullptr, qkv, S, TD, D);
    attn_sparse<<<S, 256, 0, stream>>>(qkv, csr_cnt, csr_idx, attn_o);
    gemm_mfma<64, 64, 0, true><<<dim3(D / 64, S / 64), 256, 0, stream>>>(attn_o, wb_out, b_out, x_in, y1, S, D, D);
    ln_only<bf16_t><<<S, 256, 0, stream>>>(y1, g1, be1, x1);
    gemm_mfma<32, 64, 1, false><<<dim3((D / 2) / 64, S / 32), 256, 0, stream>>>(x1, wb_1, b1, nullptr, ffh, S, D / 2, D);
    gemm_mfma<64, 64, 0, true><<<dim3(D / 64, S / 64), 256, 0, stream>>>(ffh, wb_2, b2, x1, y2, S, D, D / 2);
    ln_only<float><<<S, 256, 0, stream>>>(y2, g2, be2, out);
}